// Round 9
// baseline (94.710 us; speedup 1.0000x reference)
//
#include <hip/hip_runtime.h>

#define B_    128
#define I_    4608
#define O_    10
#define D_    16
#define NCHUNKS 2304      // I_/2
#define NIB   256         // i-blocks; 18 i = 9 chunks each
#define CPB   9           // chunks per i-block
#define CHH   5120        // halves per prepped chunk: 2 img * 5 p * 64 lane * 8
#define PSET  20480       // floats per partial set (128*10*16)

typedef _Float16 f16x2 __attribute__((ext_vector_type(2)));
typedef _Float16 f16x4 __attribute__((ext_vector_type(4)));
typedef _Float16 f16x8 __attribute__((ext_vector_type(8)));
typedef float    f32x4 __attribute__((ext_vector_type(4)));
typedef __fp16   pk16x2 __attribute__((ext_vector_type(2)));
typedef unsigned int uint2v __attribute__((ext_vector_type(2)));

__device__ __forceinline__ f16x4 pack4(float a, float b, float c, float d) {
    union { f16x4 v; pk16x2 p[2]; } u;
    u.p[0] = __builtin_amdgcn_cvt_pkrtz(a, b);
    u.p[1] = __builtin_amdgcn_cvt_pkrtz(c, d);
    return u.v;
}
__device__ __forceinline__ f16x2 splat_h2(float a) {
    union { f16x2 v; pk16x2 p; } u;
    u.p = __builtin_amdgcn_cvt_pkrtz(a, a);
    return u.v;
}
__device__ __forceinline__ void gload_lds16(const _Float16* g, _Float16* l) {
    __builtin_amdgcn_global_load_lds(
        (const __attribute__((address_space(1))) void*)g,
        (__attribute__((address_space(3))) void*)l, 16, 0, 0);
}

// ---------------------------------------------------------------------------
// Prep: W [10][4608][16][8] fp32 -> pre-fragmented f16 images, lane-major:
// pw[chunk][img][p][lane][8 halves]. img0 = Wt (u-GEMM A), img1 = P (apply A).
// sigma: row/col n -> (iloc=(n>>2)&1, k=(n>>3)*4+(n&3)).  (R6-verified)
// ---------------------------------------------------------------------------
__global__ __launch_bounds__(256)
void prep_kernel(const float* __restrict__ w, _Float16* __restrict__ pw)
{
    __shared__ float wch[2560];           // [o][iloc*128 + d*8 + k]
    const int c = blockIdx.x, t = threadIdx.x;
#pragma unroll
    for (int o = 0; o < O_; ++o)
        wch[o * 256 + t] = w[(long)o * (I_ * 128) + (long)c * 256 + t];
    __syncthreads();

    _Float16* dst = pw + (long)c * CHH;
#pragma unroll
    for (int kk = 0; kk < 5; ++kk) {
        const int sidx = t + kk * 256;            // 0..1279 f16x4 slots
        const int hg   = sidx & 1;
        const int lane = (sidx >> 1) & 63;
        const int pi   = sidx >> 7;               // 0..9
        const int p    = pi % 5;
        const int img  = pi / 5;
        const int r = lane & 15, g = lane >> 4;
        const int o = 2 * p + hg;
        f16x4 val;
        if (img == 1) {   // P: row r=d, cols n=g*4+j -> (iloc=g&1, k=(g>>1)*4+j)
            const float4 gg = *(const float4*)&wch[o * 256 + (g & 1) * 128 + r * 8 + (g >> 1) * 4];
            val = pack4(gg.x, gg.y, gg.z, gg.w);
        } else {          // Wt: row m=r (sigma), cols d=g*4+j
            const int bofs = o * 256 + ((r >> 2) & 1) * 128 + (r >> 3) * 4 + (r & 3);
            val = pack4(wch[bofs + (g * 4 + 0) * 8], wch[bofs + (g * 4 + 1) * 8],
                        wch[bofs + (g * 4 + 2) * 8], wch[bofs + (g * 4 + 3) * 8]);
        }
        *(f16x4*)(dst + (long)sidx * 4) = val;
    }
}

// ---------------------------------------------------------------------------
// MFMA routing pass, full-B blocks: grid 256 = one 9-chunk i-slice per block;
// 8 waves = 8 b-tiles (all 128 b). Each chunk staged ONCE into LDS via
// global_load_lds (async, double-buffered, 1 barrier/chunk); pw read exactly
// once from L2 per pass (no cross-block reuse -> no L2 thrash). Waves own
// disjoint b -> direct parts write, no tree. MODE 0: uniform c, P image only.
// ---------------------------------------------------------------------------
template<int MODE>
__global__ __launch_bounds__(512, 2)
void pass_kernel(const float* __restrict__ x,      // [128][4608][8]
                 const _Float16* __restrict__ pw,  // prepped frag images
                 const float* __restrict__ v,      // [128][10][16]
                 float* __restrict__ parts)        // [NIB][128][10][16]
{
    __shared__ _Float16 lds[2][CHH];

    const int tid  = threadIdx.x;
    const int lane = tid & 63;
    const int wv   = tid >> 6;
    const int bl   = lane & 15;
    const int g    = lane >> 4;
    const int ib   = blockIdx.x;
    const int c0   = ib * CPB;
    const int iloc = g & 1, kq = g >> 1;
    const int b0   = wv * 16 + bl;

    // staging: MODE1 stages both images (640 16B slots), MODE0 only P (320)
    const long srcoff = (MODE == 1) ? 0 : 2560;
    const int  pofs   = (MODE == 1) ? 2560 : 0;    // P image offset in LDS
    const bool a0 = (MODE == 1) ? true : (tid < 320);
    const bool a1 = (MODE == 1) && (tid < 128);

    auto stage = [&](int c, int buf) {
        const _Float16* pc = pw + (long)c * CHH + srcoff;
        if (a0) gload_lds16(pc + (long)tid * 8, &lds[buf][(long)tid * 8]);
        if (a1) gload_lds16(pc + (long)(tid + 512) * 8, &lds[buf][(long)(tid + 512) * 8]);
    };

    f16x4 vf[O_];
    if (MODE == 1) {
#pragma unroll
        for (int o = 0; o < O_; ++o) {
            const float4 vv = *(const float4*)(v + ((long)b0 * O_ + o) * D_ + g * 4);
            vf[o] = pack4(vv.x, vv.y, vv.z, vv.w);
        }
    }

    f32x4 S[O_];
#pragma unroll
    for (int o = 0; o < O_; ++o) S[o] = (f32x4)(0.f);

    stage(c0, 0);

#pragma unroll 1
    for (int t = 0; t < CPB; ++t) {
        __syncthreads();   // drains vmcnt: buf[t&1] staged & visible
        if (t + 1 < CPB) stage(c0 + t + 1, (t + 1) & 1);

        const int c = c0 + t;
        const float4 xq = *(const float4*)(x + ((long)b0 * I_ + 2 * c + iloc) * 8 + kq * 4);
        const _Float16* base = &lds[t & 1][0];

        float cs[O_];
        if (MODE == 1) {
            // logits: u = Wt-frag x v ; bd = sum_k u*x ; softmax over o
#pragma unroll
            for (int p = 0; p < 5; ++p) {
                const f16x8 af = *(const f16x8*)(base + p * 512 + lane * 8);
                f16x4 ae, ao;
                ae[0]=af[0]; ae[1]=af[1]; ae[2]=af[2]; ae[3]=af[3];
                ao[0]=af[4]; ao[1]=af[5]; ao[2]=af[6]; ao[3]=af[7];
                const f32x4 ua = __builtin_amdgcn_mfma_f32_16x16x16f16(ae, vf[2*p],   (f32x4)(0.f), 0, 0, 0);
                const f32x4 ub = __builtin_amdgcn_mfma_f32_16x16x16f16(ao, vf[2*p+1], (f32x4)(0.f), 0, 0, 0);
                float d0 = ua[0] * xq.x; d0 = fmaf(ua[1], xq.y, d0);
                d0 = fmaf(ua[2], xq.z, d0); d0 = fmaf(ua[3], xq.w, d0);
                float d1 = ub[0] * xq.x; d1 = fmaf(ub[1], xq.y, d1);
                d1 = fmaf(ub[2], xq.z, d1); d1 = fmaf(ub[3], xq.w, d1);
                cs[2*p] = d0; cs[2*p+1] = d1;
            }
            float ssum = 0.f;
#pragma unroll
            for (int o = 0; o < O_; ++o) {
                const unsigned int tt = __float_as_uint(cs[o]);
                const uint2v sw = __builtin_amdgcn_permlane32_swap(tt, tt, false, false);
                const float e = __expf(__uint_as_float(sw[0]) + __uint_as_float(sw[1]));
                cs[o] = e; ssum += e;
            }
            const float inv = 1.f / ssum;
#pragma unroll
            for (int o = 0; o < O_; ++o) cs[o] *= inv;
        }

        union F4 { f16x4 v; f16x2 h[2]; };
        F4 xh;
        xh.v = pack4(xq.x, xq.y, xq.z, xq.w);
#pragma unroll
        for (int p = 0; p < 5; ++p) {
            const f16x8 pf = *(const f16x8*)(base + pofs + p * 512 + lane * 8);
            f16x4 pe, po;
            pe[0]=pf[0]; pe[1]=pf[1]; pe[2]=pf[2]; pe[3]=pf[3];
            po[0]=pf[4]; po[1]=pf[5]; po[2]=pf[6]; po[3]=pf[7];
            F4 ye, yo;
            if (MODE == 0) { ye = xh; yo = xh; }
            else {
                const f16x2 ce = splat_h2(cs[2*p]);
                const f16x2 co = splat_h2(cs[2*p+1]);
                ye.h[0] = xh.h[0] * ce; ye.h[1] = xh.h[1] * ce;
                yo.h[0] = xh.h[0] * co; yo.h[1] = xh.h[1] * co;
            }
            S[2*p]   = __builtin_amdgcn_mfma_f32_16x16x16f16(pe, ye.v, S[2*p],   0, 0, 0);
            S[2*p+1] = __builtin_amdgcn_mfma_f32_16x16x16f16(po, yo.v, S[2*p+1], 0, 0, 0);
        }
    }

    // C-frag: col = b = lane&15, row = d = g*4+reg -> parts[ib][b][o][d]
#pragma unroll
    for (int o = 0; o < O_; ++o) {
        float* pp = parts + (long)ib * PSET + ((long)b0 * O_ + o) * D_ + g * 4;
        *(f32x4*)pp = S[o];
    }
}

// ---------------------------------------------------------------------------
// Reduce 256 partial sets -> s[b,o,d]; squash over d; update v_buf / out.
// Grid 1280 (one block per (b,o)); 16 groups x 16 summands.  (R5-verified)
// ---------------------------------------------------------------------------
__global__ __launch_bounds__(256)
void reduce_squash(const float* __restrict__ parts, float* __restrict__ v_buf,
                   float* __restrict__ out, float kscale, float pre, int mode)
{
    __shared__ float red2[4][16];
    const int tid  = threadIdx.x;
    const int lane = tid & 63;
    const int wv   = tid >> 6;
    const int g2   = blockIdx.x;        // (b*O + o)
    const int pg   = tid >> 4;          // 0..15
    const int d    = tid & 15;

    float s = 0.f;
#pragma unroll
    for (int k = 0; k < 16; ++k)
        s += parts[(long)(pg * 16 + k) * PSET + g2 * D_ + d];

    s += __shfl_xor(s, 16);
    s += __shfl_xor(s, 32);
    if (lane < 16) red2[wv][lane] = s;
    __syncthreads();

    if (tid < 16) {
        float tot = (red2[0][tid] + red2[1][tid]) + (red2[2][tid] + red2[3][tid]);
        tot *= pre;
        float n2 = tot * tot;
        n2 += __shfl_xor(n2, 1);
        n2 += __shfl_xor(n2, 2);
        n2 += __shfl_xor(n2, 4);
        n2 += __shfl_xor(n2, 8);
        const float n     = sqrtf(n2);
        const float scale = n2 / ((1.f + n2) * (n + 1e-8f));
        const float o_    = scale * tot;
        const int idx = g2 * D_ + tid;
        if (mode == 0)      { v_buf[idx] = o_;  out[idx]  = kscale * o_; }
        else if (mode == 1) { v_buf[idx] += o_; out[idx] += kscale * o_; }
        else                {                   out[idx] += kscale * o_; }
    }
}

// ---------------------------------------------------------------------------
extern "C" void kernel_launch(void* const* d_in, const int* in_sizes, int n_in,
                              void* d_out, int out_size, void* d_ws, size_t ws_size,
                              hipStream_t stream)
{
    const float* x = (const float*)d_in[0];   // [128,4608,8]
    const float* w = (const float*)d_in[1];   // [10,4608,16,8]
    float* out   = (float*)d_out;             // [128,10,16]
    float* parts = (float*)d_ws;                          // 256*80KB = 21 MB
    float* v_buf = parts + (long)NIB * PSET;              // 80 KB
    _Float16* pw = (_Float16*)(v_buf + B_ * O_ * D_);     // 23.6 MB frag images

    prep_kernel<<<NCHUNKS, 256, 0, stream>>>(w, pw);

    // iter 0: c = 1/10 uniform (folded via pre=0.1)
    pass_kernel<0><<<NIB, 512, 0, stream>>>(x, pw, v_buf, parts);
    reduce_squash<<<1280, 256, 0, stream>>>(parts, v_buf, out, 0.3f, 0.1f, 0);

    // iter 1: b1 = <out0, xh>
    pass_kernel<1><<<NIB, 512, 0, stream>>>(x, pw, v_buf, parts);
    reduce_squash<<<1280, 256, 0, stream>>>(parts, v_buf, out, 0.3f, 1.0f, 1);

    // iter 2: b2 = <out0 + out1, xh>
    pass_kernel<1><<<NIB, 512, 0, stream>>>(x, pw, v_buf, parts);
    reduce_squash<<<1280, 256, 0, stream>>>(parts, v_buf, out, 0.4f, 1.0f, 2);
}

// Round 10
// 66.736 us; speedup vs baseline: 1.4192x; 1.4192x over previous
//
#include <hip/hip_runtime.h>

#define B_    128
#define I_    4608
#define O_    10
#define D_    16
#define NCHUNKS 2304      // I_/2
#define NIB   64          // i-blocks; 72 i = 36 chunks each
#define CPB   36          // chunks per i-block
#define CHH   2560        // halves per prepped chunk: 5 p * 64 lane * 8 (P image only)
#define PSET  20480       // floats per partial set (128*10*16)

typedef _Float16 f16x2 __attribute__((ext_vector_type(2)));
typedef _Float16 f16x4 __attribute__((ext_vector_type(4)));
typedef _Float16 f16x8 __attribute__((ext_vector_type(8)));
typedef float    f32x4 __attribute__((ext_vector_type(4)));
typedef __fp16   pk16x2 __attribute__((ext_vector_type(2)));
typedef unsigned int uint2v __attribute__((ext_vector_type(2)));

__device__ __forceinline__ f16x4 pack4(float a, float b, float c, float d) {
    union { f16x4 v; pk16x2 p[2]; } u;
    u.p[0] = __builtin_amdgcn_cvt_pkrtz(a, b);
    u.p[1] = __builtin_amdgcn_cvt_pkrtz(c, d);
    return u.v;
}
__device__ __forceinline__ f16x2 splat_h2(float a) {
    union { f16x2 v; pk16x2 p; } u;
    u.p = __builtin_amdgcn_cvt_pkrtz(a, a);
    return u.v;
}

// ---------------------------------------------------------------------------
// Prep: W [10][4608][16][8] fp32 -> P image only, lane-major f16:
// pw[chunk][p][lane][8 halves]; apply-GEMM A-frag: row=d (lane&15),
// K-col n=4g+j with sigma(n) -> (iloc=g&1, k=(g>>1)*4+j). o-pair per 8 halves.
// (R6-verified mapping; Wt image now derived in-register in the pass.)
// ---------------------------------------------------------------------------
__global__ __launch_bounds__(256)
void prep_kernel(const float* __restrict__ w, _Float16* __restrict__ pw)
{
    __shared__ float wch[2560];           // [o][iloc*128 + d*8 + k]
    const int c = blockIdx.x, t = threadIdx.x;
#pragma unroll
    for (int o = 0; o < O_; ++o)
        wch[o * 256 + t] = w[(long)o * (I_ * 128) + (long)c * 256 + t];
    __syncthreads();

    _Float16* dst = pw + (long)c * CHH;
#pragma unroll
    for (int kk = 0; kk < 3; ++kk) {
        const int sidx = t + kk * 256;            // 0..639 f16x4 slots
        if (sidx < 640) {
            const int hg   = sidx & 1;
            const int lane = (sidx >> 1) & 63;
            const int p    = sidx >> 7;           // 0..4
            const int r = lane & 15, g = lane >> 4;
            const int o = 2 * p + hg;
            // P: row r=d, col n=g*4+j -> (iloc=g&1, k=(g>>1)*4+j)
            const float4 gg = *(const float4*)&wch[o * 256 + (g & 1) * 128 + r * 8 + (g >> 1) * 4];
            *(f16x4*)(dst + (long)sidx * 4) = pack4(gg.x, gg.y, gg.z, gg.w);
        }
    }
}

// ---------------------------------------------------------------------------
// MFMA routing pass. Grid 512 = 64 i-blocks x 8 b-groups (16 b each),
// XCD-grouped (per-XCD set: pw 1.48 MB + x 2.36 MB < 4 MB L2). 2 blocks/CU.
// Waves process disjoint chunks c0+wv+8t; P frags direct from global.
// MODE 1 logits: Wt frag derived in-register via identity-MFMA transpose
//   (mfma(P,I,0) -> C-frag == Wt A-frag values, lossless f16 roundtrip),
//   then u = mfma(Wt, v), bd = in-lane dot + permlane32_swap (R8-verified).
// End: 3-step LDS tree over waves. MODE 0: uniform c (pre=0.1 in reduce).
// ---------------------------------------------------------------------------
template<int MODE>
__global__ __launch_bounds__(512, 4)
void pass_kernel(const float* __restrict__ x,      // [128][4608][8]
                 const _Float16* __restrict__ pw,  // prepped P frag image
                 const float* __restrict__ v,      // [128][10][16]
                 float* __restrict__ parts)        // [NIB][128][10][16]
{
    __shared__ float red[4 * 2560];   // 40 KB

    const int tid  = threadIdx.x;
    const int lane = tid & 63;
    const int wv   = tid >> 6;
    const int bl   = lane & 15;
    const int g    = lane >> 4;
    const int u    = blockIdx.x;
    const int xcd  = u & 7, s = u >> 3;            // s: 0..63
    const int ib   = xcd * 8 + (s & 7);            // same-XCD blocks share ib range
    const int bg   = s >> 3;                       // 0..7
    const int c0   = ib * CPB;
    const int cend = c0 + CPB;
    const int iloc = g & 1, kq = g >> 1;
    const int b0   = bg * 16 + bl;

    // identity B-frag: I[K=4g+j][col=bl] = (4g+j == bl)
    f16x4 idf;
#pragma unroll
    for (int j = 0; j < 4; ++j) idf[j] = (_Float16)((bl == 4 * g + j) ? 1.f : 0.f);

    f16x4 vf[O_];
    if (MODE == 1) {
#pragma unroll
        for (int o = 0; o < O_; ++o) {
            const float4 vv = *(const float4*)(v + ((long)b0 * O_ + o) * D_ + g * 4);
            vf[o] = pack4(vv.x, vv.y, vv.z, vv.w);
        }
    }

    f32x4 S[O_];
#pragma unroll
    for (int o = 0; o < O_; ++o) S[o] = (f32x4)(0.f);

    const long lofs = (long)lane * 8;
    auto fragp = [&](int c, int p) {
        return (const f16x8*)(pw + (long)c * CHH + p * 512 + lofs);
    };
    auto xp = [&](int c) {
        return (const float4*)(x + ((long)b0 * I_ + 2 * c + iloc) * 8 + kq * 4);
    };

    int c = c0 + wv;
    f16x8 f1[5];
    float4 xqC, xqN;
#pragma unroll
    for (int p = 0; p < 5; ++p) f1[p] = *fragp(c, p);
    xqC = *xp(c);

#pragma unroll
    for (int t5 = 0; t5 < 5; ++t5) {
        const bool valid = (c < cend);
        int cn = c + 8; if (cn > NCHUNKS - 1) cn = NCHUNKS - 1;
        if (valid) {
            xqN = *xp(cn);

            float cs[O_];
            if (MODE == 1) {
                // logits: Wt = transpose(P) via identity MFMA; u = Wt x v;
                // bd = sum_k u*x (in-lane + permlane32_swap); softmax over o
#pragma unroll
                for (int p = 0; p < 5; ++p) {
                    f16x4 pe, po;
                    pe[0]=f1[p][0]; pe[1]=f1[p][1]; pe[2]=f1[p][2]; pe[3]=f1[p][3];
                    po[0]=f1[p][4]; po[1]=f1[p][5]; po[2]=f1[p][6]; po[3]=f1[p][7];
                    const f32x4 te = __builtin_amdgcn_mfma_f32_16x16x16f16(pe, idf, (f32x4)(0.f), 0, 0, 0);
                    const f32x4 to = __builtin_amdgcn_mfma_f32_16x16x16f16(po, idf, (f32x4)(0.f), 0, 0, 0);
                    const f16x4 ae = pack4(te[0], te[1], te[2], te[3]);
                    const f16x4 ao = pack4(to[0], to[1], to[2], to[3]);
                    const f32x4 ua = __builtin_amdgcn_mfma_f32_16x16x16f16(ae, vf[2*p],   (f32x4)(0.f), 0, 0, 0);
                    const f32x4 ub = __builtin_amdgcn_mfma_f32_16x16x16f16(ao, vf[2*p+1], (f32x4)(0.f), 0, 0, 0);
                    float d0 = ua[0] * xqC.x; d0 = fmaf(ua[1], xqC.y, d0);
                    d0 = fmaf(ua[2], xqC.z, d0); d0 = fmaf(ua[3], xqC.w, d0);
                    float d1 = ub[0] * xqC.x; d1 = fmaf(ub[1], xqC.y, d1);
                    d1 = fmaf(ub[2], xqC.z, d1); d1 = fmaf(ub[3], xqC.w, d1);
                    cs[2*p] = d0; cs[2*p+1] = d1;
                }
                float ssum = 0.f;
#pragma unroll
                for (int o = 0; o < O_; ++o) {
                    const unsigned int tt = __float_as_uint(cs[o]);
                    const uint2v sw = __builtin_amdgcn_permlane32_swap(tt, tt, false, false);
                    const float e = __expf(__uint_as_float(sw[0]) + __uint_as_float(sw[1]));
                    cs[o] = e; ssum += e;
                }
                const float inv = 1.f / ssum;
#pragma unroll
                for (int o = 0; o < O_; ++o) cs[o] *= inv;
            }

            union F4 { f16x4 v; f16x2 h[2]; };
            F4 xh;
            xh.v = pack4(xqC.x, xqC.y, xqC.z, xqC.w);
#pragma unroll
            for (int p = 0; p < 5; ++p) {
                f16x4 pe, po;
                pe[0]=f1[p][0]; pe[1]=f1[p][1]; pe[2]=f1[p][2]; pe[3]=f1[p][3];
                po[0]=f1[p][4]; po[1]=f1[p][5]; po[2]=f1[p][6]; po[3]=f1[p][7];
                F4 ye, yo;
                if (MODE == 0) { ye = xh; yo = xh; }
                else {
                    const f16x2 ce = splat_h2(cs[2*p]);
                    const f16x2 co = splat_h2(cs[2*p+1]);
                    ye.h[0] = xh.h[0] * ce; ye.h[1] = xh.h[1] * ce;
                    yo.h[0] = xh.h[0] * co; yo.h[1] = xh.h[1] * co;
                }
                S[2*p]   = __builtin_amdgcn_mfma_f32_16x16x16f16(pe, ye.v, S[2*p],   0, 0, 0);
                S[2*p+1] = __builtin_amdgcn_mfma_f32_16x16x16f16(po, yo.v, S[2*p+1], 0, 0, 0);
            }
#pragma unroll
            for (int p = 0; p < 5; ++p) f1[p] = *fragp(cn, p);
            xqC = xqN;
        }
        c += 8;
    }

    // ---- inter-wave tree reduction (waves covered disjoint chunks) ----
    auto slot = [&](int w, int o) {
        return &red[w * 2560 + o * 256 + lane * 4];
    };
#define TREE_WR(WSRC)                                                       \
    if (wv >= WSRC && wv < 2 * WSRC) {                                      \
        _Pragma("unroll") for (int o = 0; o < O_; ++o)                      \
            *(f32x4*)slot(wv - WSRC, o) = S[o];                             \
    }                                                                       \
    __syncthreads();                                                        \
    if (wv < WSRC) {                                                        \
        _Pragma("unroll") for (int o = 0; o < O_; ++o)                      \
            S[o] += *(f32x4*)slot(wv, o);                                   \
    }                                                                       \
    __syncthreads();

    TREE_WR(4)
    TREE_WR(2)
    TREE_WR(1)
#undef TREE_WR

    if (wv == 0) {
#pragma unroll
        for (int o = 0; o < O_; ++o) {
            float* pp = parts + (long)ib * PSET + ((long)b0 * O_ + o) * D_ + g * 4;
            *(f32x4*)pp = S[o];
        }
    }
}

// ---------------------------------------------------------------------------
// Reduce 64 partial sets -> s[b,o,d]; squash over d; update v_buf / out.
// Grid 1280 (one block per (b,o)).  (R6/R8-verified)
// ---------------------------------------------------------------------------
__global__ __launch_bounds__(256)
void reduce_squash(const float* __restrict__ parts, float* __restrict__ v_buf,
                   float* __restrict__ out, float kscale, float pre, int mode)
{
    __shared__ float red2[4][16];
    const int tid  = threadIdx.x;
    const int lane = tid & 63;
    const int wv   = tid >> 6;
    const int g2   = blockIdx.x;        // (b*O + o)
    const int pg   = tid >> 4;          // 0..15
    const int d    = tid & 15;

    float s = 0.f;
#pragma unroll
    for (int k = 0; k < 4; ++k)
        s += parts[(long)(pg * 4 + k) * PSET + g2 * D_ + d];

    s += __shfl_xor(s, 16);
    s += __shfl_xor(s, 32);
    if (lane < 16) red2[wv][lane] = s;
    __syncthreads();

    if (tid < 16) {
        float tot = (red2[0][tid] + red2[1][tid]) + (red2[2][tid] + red2[3][tid]);
        tot *= pre;
        float n2 = tot * tot;
        n2 += __shfl_xor(n2, 1);
        n2 += __shfl_xor(n2, 2);
        n2 += __shfl_xor(n2, 4);
        n2 += __shfl_xor(n2, 8);
        const float n     = sqrtf(n2);
        const float scale = n2 / ((1.f + n2) * (n + 1e-8f));
        const float o_    = scale * tot;
        const int idx = g2 * D_ + tid;
        if (mode == 0)      { v_buf[idx] = o_;  out[idx]  = kscale * o_; }
        else if (mode == 1) { v_buf[idx] += o_; out[idx] += kscale * o_; }
        else                {                   out[idx] += kscale * o_; }
    }
}

// ---------------------------------------------------------------------------
extern "C" void kernel_launch(void* const* d_in, const int* in_sizes, int n_in,
                              void* d_out, int out_size, void* d_ws, size_t ws_size,
                              hipStream_t stream)
{
    const float* x = (const float*)d_in[0];   // [128,4608,8]
    const float* w = (const float*)d_in[1];   // [10,4608,16,8]
    float* out   = (float*)d_out;             // [128,10,16]
    float* parts = (float*)d_ws;                          // 64*80KB = 5.24 MB
    float* v_buf = parts + (long)NIB * PSET;              // 80 KB
    _Float16* pw = (_Float16*)(v_buf + B_ * O_ * D_);     // 11.8 MB P frag image

    prep_kernel<<<NCHUNKS, 256, 0, stream>>>(w, pw);

    // iter 0: c = 1/10 uniform (folded via pre=0.1)
    pass_kernel<0><<<512, 512, 0, stream>>>(x, pw, v_buf, parts);
    reduce_squash<<<1280, 256, 0, stream>>>(parts, v_buf, out, 0.3f, 0.1f, 0);

    // iter 1: b1 = <out0, xh>
    pass_kernel<1><<<512, 512, 0, stream>>>(x, pw, v_buf, parts);
    reduce_squash<<<1280, 256, 0, stream>>>(parts, v_buf, out, 0.3f, 1.0f, 1);

    // iter 2: b2 = <out0 + out1, xh>
    pass_kernel<1><<<512, 512, 0, stream>>>(x, pw, v_buf, parts);
    reduce_squash<<<1280, 256, 0, stream>>>(parts, v_buf, out, 0.4f, 1.0f, 2);
}